// Round 7
// baseline (393.526 us; speedup 1.0000x reference)
//
#include <hip/hip_runtime.h>
#include <hip/hip_bf16.h>

#define B_ 4
#define N_ 2048
#define C_ 256
#define H_ 8
#define D_ 32

typedef __attribute__((ext_vector_type(4))) short bf16x4;
typedef __attribute__((ext_vector_type(8))) short bf16x8;
typedef __attribute__((ext_vector_type(16))) float f32x16;

static __device__ __forceinline__ float b2f(short u) {
    unsigned v = ((unsigned)(unsigned short)u) << 16;
    return __builtin_bit_cast(float, v);
}
static __device__ __forceinline__ short f2bs(float f) {
    __hip_bfloat16 h = __float2bfloat16(f);
    return __builtin_bit_cast(short, h);
}

// Fragment k-map (32x32x16 bf16): slot s (0..15), lane-half hi:
//   dd = hi*4 + (s&3) + 8*(s>>2); inverse hi=(dd>>2)&1, s=(dd&3)+4*(dd>>3)

// ---------------------------------------------------------------------------
__global__ __launch_bounds__(256) void x_relayout(const float* __restrict__ x,
                                                  short* __restrict__ xF) {
    const int idx = blockIdx.x * 256 + threadIdx.x;
    const int row = idx >> 6, c0 = (idx & 63) * 4;
    const float4 f4 = *(const float4*)(x + (size_t)row * 256 + c0);
    const int mt = row >> 5, l5 = row & 31;
    const int kt = c0 >> 5, dd0 = c0 & 31;
    const int hi = (dd0 >> 2) & 1, s0 = 4 * (dd0 >> 3);
    bf16x4 o;
    o[0] = f2bs(f4.x); o[1] = f2bs(f4.y); o[2] = f2bs(f4.z); o[3] = f2bs(f4.w);
    *(bf16x4*)(xF + (((size_t)mt * 8 + kt) * 32 + l5) * 32 + hi * 16 + s0) = o;
}

// ---------------------------------------------------------------------------
__global__ __launch_bounds__(256) void w_relayout(const float* __restrict__ Wq,
                                                  const float* __restrict__ Wo,
                                                  short* __restrict__ wqF,
                                                  short* __restrict__ woF) {
    int idx = blockIdx.x * 256 + threadIdx.x;
    const float* W; short* dst; int ncols;
    if (idx < 49152) { W = Wq; dst = wqF; ncols = 768; }
    else { idx -= 49152; W = Wo; dst = woF; ncols = 256; }
    const int f4pr = ncols >> 2;
    const int row = idx / f4pr, c0 = (idx % f4pr) * 4;
    const float4 f4 = *(const float4*)(W + (size_t)row * ncols + c0);
    const int kt = row >> 5, dd = row & 31;
    const int hi = (dd >> 2) & 1, s = (dd & 3) + 4 * (dd >> 3);
    const float vals[4] = {f4.x, f4.y, f4.z, f4.w};
#pragma unroll
    for (int j = 0; j < 4; ++j) {
        const int col = c0 + j, nt = col >> 5, l5 = col & 31;
        dst[(((size_t)nt * 8 + kt) * 32 + l5) * 32 + hi * 16 + s] = f2bs(vals[j]);
    }
}

// ---------------------------------------------------------------------------
__global__ __launch_bounds__(256) void mask_relayout(const float* __restrict__ mask,
                                                     short* __restrict__ maskF) {
    const int t = threadIdx.x;
    const int n = blockIdx.y * 64 + (t & 63);
    const int mt = blockIdx.x * 4 + (t >> 6);
    const float cf = 0.17677669529663687f * 1.4426950408889634f;
    float v[32];
    const float4* src = (const float4*)(mask + (size_t)n * N_ + mt * 32);
#pragma unroll
    for (int i = 0; i < 8; ++i) {
        const float4 f4 = src[i];
        v[i * 4 + 0] = f4.x; v[i * 4 + 1] = f4.y;
        v[i * 4 + 2] = f4.z; v[i * 4 + 3] = f4.w;
    }
#pragma unroll
    for (int hi = 0; hi < 2; ++hi) {
        bf16x8 o0, o1;
#pragma unroll
        for (int r = 0; r < 16; ++r) {
            const int crow = (r & 3) + 8 * (r >> 2) + 4 * hi;
            const short s = f2bs(cf * (0.1f + 0.9f * v[crow]));
            if (r < 8) o0[r] = s; else o1[r - 8] = s;
        }
        short* dst = maskF + ((size_t)(mt * 2 + hi) * N_ + n) * 16;
        *(bf16x8*)dst = o0;
        *(bf16x8*)(dst + 8) = o1;
    }
}

// ---------------------------------------------------------------------------
// QKV projection, MFMA (dual accumulator for MFMA ILP).
// ---------------------------------------------------------------------------
__global__ __launch_bounds__(256, 4) void qkv_mfma(const short* __restrict__ xF,
                                                   const short* __restrict__ wqF,
                                                   const float* __restrict__ bias,
                                                   short* __restrict__ qb,
                                                   short* __restrict__ kbF,
                                                   short* __restrict__ vbF) {
    __shared__ short sc[4][32 * 34];
    const int t = threadIdx.x;
    const int w = t >> 6, lane = t & 63, l5 = lane & 31, hi = lane >> 5;
    const int tile = blockIdx.x * 4 + w;
    const int nt = tile % 24, mt = tile / 24;
    f32x16 acc0, acc1;
#pragma unroll
    for (int i = 0; i < 16; ++i) { acc0[i] = 0.f; acc1[i] = 0.f; }
    const short* ap = xF + ((size_t)mt * 8 * 32) * 32 + l5 * 32 + hi * 16;
    const short* bp = wqF + ((size_t)nt * 8 * 32) * 32 + l5 * 32 + hi * 16;
#pragma unroll
    for (int kt = 0; kt < 8; kt += 2) {
        const bf16x8 a0 = *(const bf16x8*)(ap + kt * 1024);
        const bf16x8 a1 = *(const bf16x8*)(ap + kt * 1024 + 8);
        const bf16x8 b0 = *(const bf16x8*)(bp + kt * 1024);
        const bf16x8 b1 = *(const bf16x8*)(bp + kt * 1024 + 8);
        const bf16x8 a2 = *(const bf16x8*)(ap + kt * 1024 + 1024);
        const bf16x8 a3 = *(const bf16x8*)(ap + kt * 1024 + 1032);
        const bf16x8 b2 = *(const bf16x8*)(bp + kt * 1024 + 1024);
        const bf16x8 b3 = *(const bf16x8*)(bp + kt * 1024 + 1032);
        acc0 = __builtin_amdgcn_mfma_f32_32x32x16_bf16(a0, b0, acc0, 0, 0, 0);
        acc1 = __builtin_amdgcn_mfma_f32_32x32x16_bf16(a2, b2, acc1, 0, 0, 0);
        acc0 = __builtin_amdgcn_mfma_f32_32x32x16_bf16(a1, b1, acc0, 0, 0, 0);
        acc1 = __builtin_amdgcn_mfma_f32_32x32x16_bf16(a3, b3, acc1, 0, 0, 0);
    }
    const float bq = bias[nt * 32 + l5];
    short* myc = sc[w];
#pragma unroll
    for (int r = 0; r < 16; ++r)
        myc[((r & 3) + 8 * (r >> 2) + 4 * hi) * 34 + l5] =
            f2bs(acc0[r] + acc1[r] + bq);
    __syncthreads();

    const int h = nt & 7, t3 = nt >> 3;
    const int mtk = mt & 63;
    const size_t bh = (size_t)(mt >> 6) * 8 + h;
    if (t3 == 0) {
        const bf16x8 r0 = *(const bf16x8*)(myc + l5 * 34 + hi * 16);
        const bf16x8 r1 = *(const bf16x8*)(myc + l5 * 34 + hi * 16 + 8);
        short* dst = qb + (bh * N_ + (size_t)mtk * 32 + l5) * D_ + hi * 16;
        *(bf16x8*)dst = r0;
        *(bf16x8*)(dst + 8) = r1;
    } else if (t3 == 1) {
        bf16x8 o0, o1;
#pragma unroll
        for (int s = 0; s < 16; ++s) {
            const int dd = hi * 4 + (s & 3) + 8 * (s >> 2);
            const short vv = myc[l5 * 34 + dd];
            if (s < 8) o0[s] = vv; else o1[s - 8] = vv;
        }
        short* dst = kbF + ((bh * 64 + mtk) * 32 + l5) * 32 + hi * 16;
        *(bf16x8*)dst = o0;
        *(bf16x8*)(dst + 8) = o1;
    } else {
        bf16x8 o0, o1;
#pragma unroll
        for (int s = 0; s < 16; ++s) {
            const int nl = hi * 4 + (s & 3) + 8 * (s >> 2);
            const short vv = myc[nl * 34 + l5];
            if (s < 8) o0[s] = vv; else o1[s - 8] = vv;
        }
        short* dst = vbF + ((bh * 64 + mtk) * 32 + l5) * 32 + hi * 16;
        *(bf16x8*)dst = o0;
        *(bf16x8*)(dst + 8) = o1;
    }
}

// ---------------------------------------------------------------------------
// MFMA flash attention. Grid 1024 = (bh, qg64). Block = 4 waves (split-m x4),
// 64 q-rows (2-tile ILP). Software-pipelined one stage deep: loads AND the
// S^T MFMAs of tile i+1 overlap the exp/pack/PV of tile i (only accA/accB is
// loop-carried). launch_bounds (256,4): the only config that doesn't spill
// (R5: (256,8)->32 VGPR, R6: (256,6)->40 VGPR, both ~700MB scratch traffic).
// ---------------------------------------------------------------------------
__global__ __launch_bounds__(256, 4) void attn_mfma(const short* __restrict__ qb,
                                                    const short* __restrict__ kbF,
                                                    const short* __restrict__ vbF,
                                                    const short* __restrict__ maskF,
                                                    short* __restrict__ aoF) {
    __shared__ float red[4][32][33];
    __shared__ float Ls[4][32];
    const int t = threadIdx.x;
    const int w = t >> 6, lane = t & 63, l5 = lane & 31, hi = lane >> 5;
    const int hi4 = hi * 4;
    const int bh = blockIdx.x >> 5, qg = blockIdx.x & 31;
    const int q0 = qg * 64;
    const int nqA = q0 + l5, nqB = q0 + 32 + l5;

    const short* qrA = qb + ((size_t)bh * N_ + nqA) * D_;
    const short* qrB = qb + ((size_t)bh * N_ + nqB) * D_;
    const bf16x8 qfA0 = __builtin_shufflevector(*(const bf16x4*)(qrA + hi4),
                                                *(const bf16x4*)(qrA + hi4 + 8),
                                                0, 1, 2, 3, 4, 5, 6, 7);
    const bf16x8 qfA1 = __builtin_shufflevector(*(const bf16x4*)(qrA + hi4 + 16),
                                                *(const bf16x4*)(qrA + hi4 + 24),
                                                0, 1, 2, 3, 4, 5, 6, 7);
    const bf16x8 qfB0 = __builtin_shufflevector(*(const bf16x4*)(qrB + hi4),
                                                *(const bf16x4*)(qrB + hi4 + 8),
                                                0, 1, 2, 3, 4, 5, 6, 7);
    const bf16x8 qfB1 = __builtin_shufflevector(*(const bf16x4*)(qrB + hi4 + 16),
                                                *(const bf16x4*)(qrB + hi4 + 24),
                                                0, 1, 2, 3, 4, 5, 6, 7);
    f32x16 accA, accB;
#pragma unroll
    for (int i = 0; i < 16; ++i) { accA[i] = 0.f; accB[i] = 0.f; }
    float lsA0 = 0.f, lsA1 = 0.f, lsB0 = 0.f, lsB1 = 0.f;

    const size_t fragbase = (size_t)bh * 64 * 1024;
    const size_t lofs = (size_t)l5 * 32 + hi * 16;

    // ---- pipeline stage registers (tile "c" = current) ----
    bf16x8 vf0c, vf1c, mA0c, mA1c, mB0c, mB1c;
    f32x16 sAc, sBc;
    {   // prologue: stage tile 0 of this wave
        const int mt = w * 16;
        const short* kp = kbF + fragbase + (size_t)mt * 1024 + lofs;
        const bf16x8 af0 = *(const bf16x8*)kp;
        const bf16x8 af1 = *(const bf16x8*)(kp + 8);
        const short* vp = vbF + fragbase + (size_t)mt * 1024 + lofs;
        vf0c = *(const bf16x8*)vp;
        vf1c = *(const bf16x8*)(vp + 8);
        const short* mpA = maskF + ((size_t)(mt * 2 + hi) * N_ + nqA) * 16;
        const short* mpB = maskF + ((size_t)(mt * 2 + hi) * N_ + nqB) * 16;
        mA0c = *(const bf16x8*)mpA;
        mA1c = *(const bf16x8*)(mpA + 8);
        mB0c = *(const bf16x8*)mpB;
        mB1c = *(const bf16x8*)(mpB + 8);
#pragma unroll
        for (int j = 0; j < 16; ++j) { sAc[j] = 0.f; sBc[j] = 0.f; }
        sAc = __builtin_amdgcn_mfma_f32_32x32x16_bf16(af0, qfA0, sAc, 0, 0, 0);
        sBc = __builtin_amdgcn_mfma_f32_32x32x16_bf16(af0, qfB0, sBc, 0, 0, 0);
        sAc = __builtin_amdgcn_mfma_f32_32x32x16_bf16(af1, qfA1, sAc, 0, 0, 0);
        sBc = __builtin_amdgcn_mfma_f32_32x32x16_bf16(af1, qfB1, sBc, 0, 0, 0);
    }

#pragma unroll
    for (int i = 0; i < 16; ++i) {
        // ---- stage tile i+1 (loads + S^T MFMAs), independent of tile i ----
        bf16x8 vf0n, vf1n, mA0n, mA1n, mB0n, mB1n;
        f32x16 sAn, sBn;
        if (i < 15) {
            const int mt = w * 16 + i + 1;
            const short* kp = kbF + fragbase + (size_t)mt * 1024 + lofs;
            const bf16x8 af0 = *(const bf16x8*)kp;
            const bf16x8 af1 = *(const bf16x8*)(kp + 8);
            const short* vp = vbF + fragbase + (size_t)mt * 1024 + lofs;
            vf0n = *(const bf16x8*)vp;
            vf1n = *(const bf16x8*)(vp + 8);
            const short* mpA = maskF + ((size_t)(mt * 2 + hi) * N_ + nqA) * 16;
            const short* mpB = maskF + ((size_t)(mt * 2 + hi) * N_ + nqB) * 16;
            mA0n = *(const bf16x8*)mpA;
            mA1n = *(const bf16x8*)(mpA + 8);
            mB0n = *(const bf16x8*)mpB;
            mB1n = *(const bf16x8*)(mpB + 8);
#pragma unroll
            for (int j = 0; j < 16; ++j) { sAn[j] = 0.f; sBn[j] = 0.f; }
            sAn = __builtin_amdgcn_mfma_f32_32x32x16_bf16(af0, qfA0, sAn, 0, 0, 0);
            sBn = __builtin_amdgcn_mfma_f32_32x32x16_bf16(af0, qfB0, sBn, 0, 0, 0);
            sAn = __builtin_amdgcn_mfma_f32_32x32x16_bf16(af1, qfA1, sAn, 0, 0, 0);
            sBn = __builtin_amdgcn_mfma_f32_32x32x16_bf16(af1, qfB1, sBn, 0, 0, 0);
        }

        // ---- consume tile i: exp, pack, PV ----
        bf16x8 pfA0, pfA1, pfB0, pfB1;
#pragma unroll
        for (int r = 0; r < 16; ++r) {
            const float fmA = b2f(r < 8 ? mA0c[r] : mA1c[r - 8]);
            const float fmB = b2f(r < 8 ? mB0c[r] : mB1c[r - 8]);
            const float pA = __builtin_amdgcn_exp2f(sAc[r] * fmA);
            const float pB = __builtin_amdgcn_exp2f(sBc[r] * fmB);
            if (r < 8) { lsA0 += pA; lsB0 += pB; }
            else       { lsA1 += pA; lsB1 += pB; }
            const short hA = f2bs(pA), hB = f2bs(pB);
            if (r < 8) { pfA0[r] = hA; pfB0[r] = hB; }
            else       { pfA1[r - 8] = hA; pfB1[r - 8] = hB; }
        }
        accA = __builtin_amdgcn_mfma_f32_32x32x16_bf16(vf0c, pfA0, accA, 0, 0, 0);
        accB = __builtin_amdgcn_mfma_f32_32x32x16_bf16(vf0c, pfB0, accB, 0, 0, 0);
        accA = __builtin_amdgcn_mfma_f32_32x32x16_bf16(vf1c, pfA1, accA, 0, 0, 0);
        accB = __builtin_amdgcn_mfma_f32_32x32x16_bf16(vf1c, pfB1, accB, 0, 0, 0);

        // ---- rotate pipeline ----
        if (i < 15) {
            vf0c = vf0n; vf1c = vf1n;
            mA0c = mA0n; mA1c = mA1n; mB0c = mB0n; mB1c = mB1n;
            sAc = sAn; sBc = sBn;
        }
    }
    const float lsA = lsA0 + lsA1, lsB = lsB0 + lsB1;

    // two reduction rounds (one per q-tile), reusing the same LDS buffer
    const int h = bh & 7;
    const int gmtb = (bh >> 3) * 64 + qg * 2;
#pragma unroll
    for (int tq = 0; tq < 2; ++tq) {
        if (tq) __syncthreads();
        const float lsum = tq ? lsB : lsA;
        const f32x16 acc = tq ? accB : accA;
        const float lt = lsum + __shfl_xor(lsum, 32);
        Ls[w][l5] = lt;
#pragma unroll
        for (int r = 0; r < 16; ++r)
            red[w][(r & 3) + 8 * (r >> 2) + hi4][l5] = acc[r];
        __syncthreads();
        const int row = t & 31, hi2 = (t >> 5) & 1, sh = t >> 6;
        const float inv = 1.0f / (Ls[0][row] + Ls[1][row] + Ls[2][row] + Ls[3][row]);
        bf16x4 o;
#pragma unroll
        for (int j = 0; j < 4; ++j) {
            const int dd = hi2 * 4 + j + 8 * sh;
            o[j] = f2bs((red[0][dd][row] + red[1][dd][row] +
                         red[2][dd][row] + red[3][dd][row]) * inv);
        }
        const size_t gmt = gmtb + tq;
        *(bf16x4*)(aoF + ((gmt * 8 + h) * 32 + row) * 32 + hi2 * 16 + sh * 4) = o;
    }
}

// ---------------------------------------------------------------------------
// Output projection, MFMA (dual accumulator).
// ---------------------------------------------------------------------------
__global__ __launch_bounds__(256, 4) void out_mfma(const short* __restrict__ aoF,
                                                   const short* __restrict__ woF,
                                                   const float* __restrict__ bias,
                                                   float* __restrict__ out) {
    const int t = threadIdx.x;
    const int w = t >> 6, lane = t & 63, l5 = lane & 31, hi = lane >> 5;
    const int tile = blockIdx.x * 4 + w;
    const int nt = tile & 7, mt = tile >> 3;
    f32x16 acc0, acc1;
#pragma unroll
    for (int i = 0; i < 16; ++i) { acc0[i] = 0.f; acc1[i] = 0.f; }
    const short* ap = aoF + (size_t)mt * 8192 + l5 * 32 + hi * 16;
    const short* bp = woF + (size_t)nt * 8192 + l5 * 32 + hi * 16;
#pragma unroll
    for (int kt = 0; kt < 8; kt += 2) {
        const bf16x8 a0 = *(const bf16x8*)(ap + kt * 1024);
        const bf16x8 a1 = *(const bf16x8*)(ap + kt * 1024 + 8);
        const bf16x8 b0 = *(const bf16x8*)(bp + kt * 1024);
        const bf16x8 b1 = *(const bf16x8*)(bp + kt * 1024 + 8);
        const bf16x8 a2 = *(const bf16x8*)(ap + kt * 1024 + 1024);
        const bf16x8 a3 = *(const bf16x8*)(ap + kt * 1024 + 1032);
        const bf16x8 b2 = *(const bf16x8*)(bp + kt * 1024 + 1024);
        const bf16x8 b3 = *(const bf16x8*)(bp + kt * 1024 + 1032);
        acc0 = __builtin_amdgcn_mfma_f32_32x32x16_bf16(a0, b0, acc0, 0, 0, 0);
        acc1 = __builtin_amdgcn_mfma_f32_32x32x16_bf16(a2, b2, acc1, 0, 0, 0);
        acc0 = __builtin_amdgcn_mfma_f32_32x32x16_bf16(a1, b1, acc0, 0, 0, 0);
        acc1 = __builtin_amdgcn_mfma_f32_32x32x16_bf16(a3, b3, acc1, 0, 0, 0);
    }
    const float bo = bias[nt * 32 + l5];
#pragma unroll
    for (int r = 0; r < 16; ++r) {
        const int crow = (r & 3) + 8 * (r >> 2) + 4 * hi;
        out[(size_t)(mt * 32 + crow) * 256 + nt * 32 + l5] =
            acc0[r] + acc1[r] + bo;
    }
}

extern "C" void kernel_launch(void* const* d_in, const int* in_sizes, int n_in,
                              void* d_out, int out_size, void* d_ws, size_t ws_size,
                              hipStream_t stream) {
    const float* x = (const float*)d_in[0];
    const float* mask = (const float*)d_in[1];
    const float* W_qkv = (const float*)d_in[2];
    const float* b_qkv = (const float*)d_in[3];
    const float* W_out = (const float*)d_in[4];
    const float* b_out = (const float*)d_in[5];
    float* out = (float*)d_out;

    const size_t per = (size_t)B_ * H_ * N_ * D_;  // 2,097,152
    short* qb = (short*)d_ws;
    short* kbF = qb + per;
    short* vbF = kbF + per;
    short* maskF = vbF + per;            // N*N = 4,194,304 shorts
    short* xF = maskF + (size_t)N_ * N_; // 2,097,152 shorts
    short* wqF = xF + per;               // 196,608 shorts
    short* woF = wqF + 196608;           // 65,536 shorts
    short* aoF = xF;                     // reuse xF (consumed by qkv_mfma)

    x_relayout<<<2048, 256, 0, stream>>>(x, xF);
    w_relayout<<<256, 256, 0, stream>>>(W_qkv, W_out, wqF, woF);
    mask_relayout<<<dim3(16, 32), 256, 0, stream>>>(mask, maskF);
    qkv_mfma<<<1536, 256, 0, stream>>>(xF, wqF, b_qkv, qb, kbF, vbF);
    attn_mfma<<<1024, 256, 0, stream>>>(qb, kbF, vbF, maskF, aoF);
    out_mfma<<<512, 256, 0, stream>>>(aoF, woF, b_out, out);
}

// Round 8
// 101.838 us; speedup vs baseline: 3.8642x; 3.8642x over previous
//
#include <hip/hip_runtime.h>
#include <hip/hip_bf16.h>

#define B_ 4
#define N_ 2048
#define C_ 256
#define H_ 8
#define D_ 32

typedef __attribute__((ext_vector_type(4))) short bf16x4;
typedef __attribute__((ext_vector_type(8))) short bf16x8;
typedef __attribute__((ext_vector_type(16))) float f32x16;

static __device__ __forceinline__ float b2f(short u) {
    unsigned v = ((unsigned)(unsigned short)u) << 16;
    return __builtin_bit_cast(float, v);
}
static __device__ __forceinline__ short f2bs(float f) {
    __hip_bfloat16 h = __float2bfloat16(f);
    return __builtin_bit_cast(short, h);
}

// Fragment k-map (32x32x16 bf16): slot s (0..15), lane-half hi:
//   dd = hi*4 + (s&3) + 8*(s>>2); inverse hi=(dd>>2)&1, s=(dd&3)+4*(dd>>3)
// REGISTER BUDGET NOTE: attn body = 64 arch VGPR + ~64 acc = 128/thread,
// exactly the 4-waves/EU unified-RF budget. R5/R6 (tighter caps) and R7
// (software pipeline, +80 regs) all spilled to scratch (400-900 MB traffic).
// Do not add live state to attn_mfma; scale via grid only.

// ---------------------------------------------------------------------------
__global__ __launch_bounds__(256) void x_relayout(const float* __restrict__ x,
                                                  short* __restrict__ xF) {
    const int idx = blockIdx.x * 256 + threadIdx.x;
    const int row = idx >> 6, c0 = (idx & 63) * 4;
    const float4 f4 = *(const float4*)(x + (size_t)row * 256 + c0);
    const int mt = row >> 5, l5 = row & 31;
    const int kt = c0 >> 5, dd0 = c0 & 31;
    const int hi = (dd0 >> 2) & 1, s0 = 4 * (dd0 >> 3);
    bf16x4 o;
    o[0] = f2bs(f4.x); o[1] = f2bs(f4.y); o[2] = f2bs(f4.z); o[3] = f2bs(f4.w);
    *(bf16x4*)(xF + (((size_t)mt * 8 + kt) * 32 + l5) * 32 + hi * 16 + s0) = o;
}

// ---------------------------------------------------------------------------
__global__ __launch_bounds__(256) void w_relayout(const float* __restrict__ Wq,
                                                  const float* __restrict__ Wo,
                                                  short* __restrict__ wqF,
                                                  short* __restrict__ woF) {
    int idx = blockIdx.x * 256 + threadIdx.x;
    const float* W; short* dst; int ncols;
    if (idx < 49152) { W = Wq; dst = wqF; ncols = 768; }
    else { idx -= 49152; W = Wo; dst = woF; ncols = 256; }
    const int f4pr = ncols >> 2;
    const int row = idx / f4pr, c0 = (idx % f4pr) * 4;
    const float4 f4 = *(const float4*)(W + (size_t)row * ncols + c0);
    const int kt = row >> 5, dd = row & 31;
    const int hi = (dd >> 2) & 1, s = (dd & 3) + 4 * (dd >> 3);
    const float vals[4] = {f4.x, f4.y, f4.z, f4.w};
#pragma unroll
    for (int j = 0; j < 4; ++j) {
        const int col = c0 + j, nt = col >> 5, l5 = col & 31;
        dst[(((size_t)nt * 8 + kt) * 32 + l5) * 32 + hi * 16 + s] = f2bs(vals[j]);
    }
}

// ---------------------------------------------------------------------------
__global__ __launch_bounds__(256) void mask_relayout(const float* __restrict__ mask,
                                                     short* __restrict__ maskF) {
    const int t = threadIdx.x;
    const int n = blockIdx.y * 64 + (t & 63);
    const int mt = blockIdx.x * 4 + (t >> 6);
    const float cf = 0.17677669529663687f * 1.4426950408889634f;
    float v[32];
    const float4* src = (const float4*)(mask + (size_t)n * N_ + mt * 32);
#pragma unroll
    for (int i = 0; i < 8; ++i) {
        const float4 f4 = src[i];
        v[i * 4 + 0] = f4.x; v[i * 4 + 1] = f4.y;
        v[i * 4 + 2] = f4.z; v[i * 4 + 3] = f4.w;
    }
#pragma unroll
    for (int hi = 0; hi < 2; ++hi) {
        bf16x8 o0, o1;
#pragma unroll
        for (int r = 0; r < 16; ++r) {
            const int crow = (r & 3) + 8 * (r >> 2) + 4 * hi;
            const short s = f2bs(cf * (0.1f + 0.9f * v[crow]));
            if (r < 8) o0[r] = s; else o1[r - 8] = s;
        }
        short* dst = maskF + ((size_t)(mt * 2 + hi) * N_ + n) * 16;
        *(bf16x8*)dst = o0;
        *(bf16x8*)(dst + 8) = o1;
    }
}

// ---------------------------------------------------------------------------
// QKV projection, MFMA (dual accumulator for MFMA ILP).
// ---------------------------------------------------------------------------
__global__ __launch_bounds__(256, 4) void qkv_mfma(const short* __restrict__ xF,
                                                   const short* __restrict__ wqF,
                                                   const float* __restrict__ bias,
                                                   short* __restrict__ qb,
                                                   short* __restrict__ kbF,
                                                   short* __restrict__ vbF) {
    __shared__ short sc[4][32 * 34];
    const int t = threadIdx.x;
    const int w = t >> 6, lane = t & 63, l5 = lane & 31, hi = lane >> 5;
    const int tile = blockIdx.x * 4 + w;
    const int nt = tile % 24, mt = tile / 24;
    f32x16 acc0, acc1;
#pragma unroll
    for (int i = 0; i < 16; ++i) { acc0[i] = 0.f; acc1[i] = 0.f; }
    const short* ap = xF + ((size_t)mt * 8 * 32) * 32 + l5 * 32 + hi * 16;
    const short* bp = wqF + ((size_t)nt * 8 * 32) * 32 + l5 * 32 + hi * 16;
#pragma unroll
    for (int kt = 0; kt < 8; kt += 2) {
        const bf16x8 a0 = *(const bf16x8*)(ap + kt * 1024);
        const bf16x8 a1 = *(const bf16x8*)(ap + kt * 1024 + 8);
        const bf16x8 b0 = *(const bf16x8*)(bp + kt * 1024);
        const bf16x8 b1 = *(const bf16x8*)(bp + kt * 1024 + 8);
        const bf16x8 a2 = *(const bf16x8*)(ap + kt * 1024 + 1024);
        const bf16x8 a3 = *(const bf16x8*)(ap + kt * 1024 + 1032);
        const bf16x8 b2 = *(const bf16x8*)(bp + kt * 1024 + 1024);
        const bf16x8 b3 = *(const bf16x8*)(bp + kt * 1024 + 1032);
        acc0 = __builtin_amdgcn_mfma_f32_32x32x16_bf16(a0, b0, acc0, 0, 0, 0);
        acc1 = __builtin_amdgcn_mfma_f32_32x32x16_bf16(a2, b2, acc1, 0, 0, 0);
        acc0 = __builtin_amdgcn_mfma_f32_32x32x16_bf16(a1, b1, acc0, 0, 0, 0);
        acc1 = __builtin_amdgcn_mfma_f32_32x32x16_bf16(a3, b3, acc1, 0, 0, 0);
    }
    const float bq = bias[nt * 32 + l5];
    short* myc = sc[w];
#pragma unroll
    for (int r = 0; r < 16; ++r)
        myc[((r & 3) + 8 * (r >> 2) + 4 * hi) * 34 + l5] =
            f2bs(acc0[r] + acc1[r] + bq);
    __syncthreads();

    const int h = nt & 7, t3 = nt >> 3;
    const int mtk = mt & 63;
    const size_t bh = (size_t)(mt >> 6) * 8 + h;
    if (t3 == 0) {
        const bf16x8 r0 = *(const bf16x8*)(myc + l5 * 34 + hi * 16);
        const bf16x8 r1 = *(const bf16x8*)(myc + l5 * 34 + hi * 16 + 8);
        short* dst = qb + (bh * N_ + (size_t)mtk * 32 + l5) * D_ + hi * 16;
        *(bf16x8*)dst = r0;
        *(bf16x8*)(dst + 8) = r1;
    } else if (t3 == 1) {
        bf16x8 o0, o1;
#pragma unroll
        for (int s = 0; s < 16; ++s) {
            const int dd = hi * 4 + (s & 3) + 8 * (s >> 2);
            const short vv = myc[l5 * 34 + dd];
            if (s < 8) o0[s] = vv; else o1[s - 8] = vv;
        }
        short* dst = kbF + ((bh * 64 + mtk) * 32 + l5) * 32 + hi * 16;
        *(bf16x8*)dst = o0;
        *(bf16x8*)(dst + 8) = o1;
    } else {
        bf16x8 o0, o1;
#pragma unroll
        for (int s = 0; s < 16; ++s) {
            const int nl = hi * 4 + (s & 3) + 8 * (s >> 2);
            const short vv = myc[nl * 34 + l5];
            if (s < 8) o0[s] = vv; else o1[s - 8] = vv;
        }
        short* dst = vbF + ((bh * 64 + mtk) * 32 + l5) * 32 + hi * 16;
        *(bf16x8*)dst = o0;
        *(bf16x8*)(dst + 8) = o1;
    }
}

// ---------------------------------------------------------------------------
// MFMA flash attention main. Grid 2048 = (bh, qg64, mh). Block = 4 waves,
// split-m x4 within the block's 32-m-tile half; 64 q-rows (2-tile ILP).
// R4 body verbatim (the only no-spill configuration), writes UNNORMALIZED
// fp32 partials + partial row-sums (exact: no max-rescale).
// ---------------------------------------------------------------------------
__global__ __launch_bounds__(256, 4) void attn_mfma(const short* __restrict__ qb,
                                                    const short* __restrict__ kbF,
                                                    const short* __restrict__ vbF,
                                                    const short* __restrict__ maskF,
                                                    float* __restrict__ Pbuf,
                                                    float* __restrict__ Lbuf) {
    __shared__ float red[4][32][33];
    __shared__ float Ls[4][32];
    const int t = threadIdx.x;
    const int w = t >> 6, lane = t & 63, l5 = lane & 31, hi = lane >> 5;
    const int hi4 = hi * 4;
    const int blk = blockIdx.x;
    const int bh = blk >> 6, qg = (blk >> 1) & 31, mh = blk & 1;
    const int q0 = qg * 64;
    const int nqA = q0 + l5, nqB = q0 + 32 + l5;

    const short* qrA = qb + ((size_t)bh * N_ + nqA) * D_;
    const short* qrB = qb + ((size_t)bh * N_ + nqB) * D_;
    const bf16x8 qfA0 = __builtin_shufflevector(*(const bf16x4*)(qrA + hi4),
                                                *(const bf16x4*)(qrA + hi4 + 8),
                                                0, 1, 2, 3, 4, 5, 6, 7);
    const bf16x8 qfA1 = __builtin_shufflevector(*(const bf16x4*)(qrA + hi4 + 16),
                                                *(const bf16x4*)(qrA + hi4 + 24),
                                                0, 1, 2, 3, 4, 5, 6, 7);
    const bf16x8 qfB0 = __builtin_shufflevector(*(const bf16x4*)(qrB + hi4),
                                                *(const bf16x4*)(qrB + hi4 + 8),
                                                0, 1, 2, 3, 4, 5, 6, 7);
    const bf16x8 qfB1 = __builtin_shufflevector(*(const bf16x4*)(qrB + hi4 + 16),
                                                *(const bf16x4*)(qrB + hi4 + 24),
                                                0, 1, 2, 3, 4, 5, 6, 7);
    f32x16 accA, accB;
#pragma unroll
    for (int i = 0; i < 16; ++i) { accA[i] = 0.f; accB[i] = 0.f; }
    float lsA0 = 0.f, lsA1 = 0.f, lsB0 = 0.f, lsB1 = 0.f;

    const size_t fragbase = (size_t)bh * 64 * 1024;
#pragma unroll 4
    for (int i = 0; i < 8; ++i) {
        const int mt = mh * 32 + w * 8 + i;
        const short* mpA = maskF + ((size_t)(mt * 2 + hi) * N_ + nqA) * 16;
        const short* mpB = maskF + ((size_t)(mt * 2 + hi) * N_ + nqB) * 16;
        const bf16x8 mA0 = *(const bf16x8*)mpA;
        const bf16x8 mA1 = *(const bf16x8*)(mpA + 8);
        const bf16x8 mB0 = *(const bf16x8*)mpB;
        const bf16x8 mB1 = *(const bf16x8*)(mpB + 8);
        const short* vp = vbF + fragbase + (size_t)mt * 1024 + l5 * 32 + hi * 16;
        const bf16x8 vf0 = *(const bf16x8*)vp;
        const bf16x8 vf1 = *(const bf16x8*)(vp + 8);

        const short* kp = kbF + fragbase + (size_t)mt * 1024 + l5 * 32 + hi * 16;
        const bf16x8 af0 = *(const bf16x8*)kp;
        const bf16x8 af1 = *(const bf16x8*)(kp + 8);
        f32x16 sA, sB;
#pragma unroll
        for (int j = 0; j < 16; ++j) { sA[j] = 0.f; sB[j] = 0.f; }
        sA = __builtin_amdgcn_mfma_f32_32x32x16_bf16(af0, qfA0, sA, 0, 0, 0);
        sB = __builtin_amdgcn_mfma_f32_32x32x16_bf16(af0, qfB0, sB, 0, 0, 0);
        sA = __builtin_amdgcn_mfma_f32_32x32x16_bf16(af1, qfA1, sA, 0, 0, 0);
        sB = __builtin_amdgcn_mfma_f32_32x32x16_bf16(af1, qfB1, sB, 0, 0, 0);

        bf16x8 pfA0, pfA1, pfB0, pfB1;
#pragma unroll
        for (int r = 0; r < 16; ++r) {
            const float fmA = b2f(r < 8 ? mA0[r] : mA1[r - 8]);
            const float fmB = b2f(r < 8 ? mB0[r] : mB1[r - 8]);
            const float pA = __builtin_amdgcn_exp2f(sA[r] * fmA);
            const float pB = __builtin_amdgcn_exp2f(sB[r] * fmB);
            if (r < 8) { lsA0 += pA; lsB0 += pB; }
            else       { lsA1 += pA; lsB1 += pB; }
            const short hA = f2bs(pA), hB = f2bs(pB);
            if (r < 8) { pfA0[r] = hA; pfB0[r] = hB; }
            else       { pfA1[r - 8] = hA; pfB1[r - 8] = hB; }
        }
        accA = __builtin_amdgcn_mfma_f32_32x32x16_bf16(vf0, pfA0, accA, 0, 0, 0);
        accB = __builtin_amdgcn_mfma_f32_32x32x16_bf16(vf0, pfB0, accB, 0, 0, 0);
        accA = __builtin_amdgcn_mfma_f32_32x32x16_bf16(vf1, pfA1, accA, 0, 0, 0);
        accB = __builtin_amdgcn_mfma_f32_32x32x16_bf16(vf1, pfB1, accB, 0, 0, 0);
    }
    const float lsA = lsA0 + lsA1, lsB = lsB0 + lsB1;

#pragma unroll
    for (int tq = 0; tq < 2; ++tq) {
        if (tq) __syncthreads();
        const float lsum = tq ? lsB : lsA;
        const f32x16 acc = tq ? accB : accA;
        const float lt = lsum + __shfl_xor(lsum, 32);
        Ls[w][l5] = lt;
#pragma unroll
        for (int r = 0; r < 16; ++r)
            red[w][(r & 3) + 8 * (r >> 2) + hi4][l5] = acc[r];
        __syncthreads();
        const int row = t & 31, hi2 = (t >> 5) & 1, sh = t >> 6;
        float4 o;
        float* op = &o.x;
#pragma unroll
        for (int j = 0; j < 4; ++j) {
            const int dd = hi2 * 4 + j + 8 * sh;
            op[j] = red[0][dd][row] + red[1][dd][row] +
                    red[2][dd][row] + red[3][dd][row];
        }
        *(float4*)(Pbuf + ((size_t)blk * 64 + tq * 32 + row) * 32 +
                   hi2 * 4 + sh * 8) = o;
        if (t < 32)
            Lbuf[(size_t)blk * 64 + tq * 32 + t] =
                Ls[0][t] + Ls[1][t] + Ls[2][t] + Ls[3][t];
    }
}

// ---------------------------------------------------------------------------
// Combine: sum the 2 m-half partials, normalize, emit bf16 aoF fragments.
// ---------------------------------------------------------------------------
__global__ __launch_bounds__(256) void attn_combine(const float* __restrict__ Pbuf,
                                                    const float* __restrict__ Lbuf,
                                                    short* __restrict__ aoF) {
    const int pg = blockIdx.x;           // (bh*32 + qg)
    const int bh = pg >> 5, qg = pg & 31;
    const int t = threadIdx.x;
    const int qq = t >> 2, ds = (t & 3) * 8;
    const size_t b0 = ((size_t)(pg * 2) * 64 + qq) * 32 + ds;
    const size_t b1 = b0 + 2048;
    const float4 a0 = *(const float4*)(Pbuf + b0);
    const float4 a1 = *(const float4*)(Pbuf + b0 + 4);
    const float4 c0 = *(const float4*)(Pbuf + b1);
    const float4 c1 = *(const float4*)(Pbuf + b1 + 4);
    const float L = Lbuf[(size_t)(pg * 2) * 64 + qq] +
                    Lbuf[(size_t)(pg * 2 + 1) * 64 + qq];
    const float inv = 1.0f / L;
    bf16x4 o0, o1;
    o0[0] = f2bs((a0.x + c0.x) * inv); o0[1] = f2bs((a0.y + c0.y) * inv);
    o0[2] = f2bs((a0.z + c0.z) * inv); o0[3] = f2bs((a0.w + c0.w) * inv);
    o1[0] = f2bs((a1.x + c1.x) * inv); o1[1] = f2bs((a1.y + c1.y) * inv);
    o1[2] = f2bs((a1.z + c1.z) * inv); o1[3] = f2bs((a1.w + c1.w) * inv);
    const int h = bh & 7;
    const int gq = qg * 64 + qq;
    const int gmt = (bh >> 3) * 64 + (gq >> 5), row = gq & 31;
    short* base = aoF + (((size_t)gmt * 8 + h) * 32 + row) * 32;
    *(bf16x4*)(base + 4 * (ds >> 3)) = o0;
    *(bf16x4*)(base + 16 + 4 * (ds >> 3)) = o1;
}

// ---------------------------------------------------------------------------
// Output projection, MFMA (dual accumulator).
// ---------------------------------------------------------------------------
__global__ __launch_bounds__(256, 4) void out_mfma(const short* __restrict__ aoF,
                                                   const short* __restrict__ woF,
                                                   const float* __restrict__ bias,
                                                   float* __restrict__ out) {
    const int t = threadIdx.x;
    const int w = t >> 6, lane = t & 63, l5 = lane & 31, hi = lane >> 5;
    const int tile = blockIdx.x * 4 + w;
    const int nt = tile & 7, mt = tile >> 3;
    f32x16 acc0, acc1;
#pragma unroll
    for (int i = 0; i < 16; ++i) { acc0[i] = 0.f; acc1[i] = 0.f; }
    const short* ap = aoF + (size_t)mt * 8192 + l5 * 32 + hi * 16;
    const short* bp = woF + (size_t)nt * 8192 + l5 * 32 + hi * 16;
#pragma unroll
    for (int kt = 0; kt < 8; kt += 2) {
        const bf16x8 a0 = *(const bf16x8*)(ap + kt * 1024);
        const bf16x8 a1 = *(const bf16x8*)(ap + kt * 1024 + 8);
        const bf16x8 b0 = *(const bf16x8*)(bp + kt * 1024);
        const bf16x8 b1 = *(const bf16x8*)(bp + kt * 1024 + 8);
        const bf16x8 a2 = *(const bf16x8*)(ap + kt * 1024 + 1024);
        const bf16x8 a3 = *(const bf16x8*)(ap + kt * 1024 + 1032);
        const bf16x8 b2 = *(const bf16x8*)(bp + kt * 1024 + 1024);
        const bf16x8 b3 = *(const bf16x8*)(bp + kt * 1024 + 1032);
        acc0 = __builtin_amdgcn_mfma_f32_32x32x16_bf16(a0, b0, acc0, 0, 0, 0);
        acc1 = __builtin_amdgcn_mfma_f32_32x32x16_bf16(a2, b2, acc1, 0, 0, 0);
        acc0 = __builtin_amdgcn_mfma_f32_32x32x16_bf16(a1, b1, acc0, 0, 0, 0);
        acc1 = __builtin_amdgcn_mfma_f32_32x32x16_bf16(a3, b3, acc1, 0, 0, 0);
    }
    const float bo = bias[nt * 32 + l5];
#pragma unroll
    for (int r = 0; r < 16; ++r) {
        const int crow = (r & 3) + 8 * (r >> 2) + 4 * hi;
        out[(size_t)(mt * 32 + crow) * 256 + nt * 32 + l5] =
            acc0[r] + acc1[r] + bo;
    }
}

extern "C" void kernel_launch(void* const* d_in, const int* in_sizes, int n_in,
                              void* d_out, int out_size, void* d_ws, size_t ws_size,
                              hipStream_t stream) {
    const float* x = (const float*)d_in[0];
    const float* mask = (const float*)d_in[1];
    const float* W_qkv = (const float*)d_in[2];
    const float* b_qkv = (const float*)d_in[3];
    const float* W_out = (const float*)d_in[4];
    const float* b_out = (const float*)d_in[5];
    float* out = (float*)d_out;

    const size_t per = (size_t)B_ * H_ * N_ * D_;  // 2,097,152
    short* qb = (short*)d_ws;
    short* kbF = qb + per;
    short* vbF = kbF + per;
    short* maskF = vbF + per;            // N*N = 4,194,304 shorts
    short* xF = maskF + (size_t)N_ * N_; // 2,097,152 shorts
    short* wqF = xF + per;               // 196,608 shorts
    short* woF = wqF + 196608;           // 65,536 shorts
    float* Pbuf = (float*)(woF + 65536); // 4,194,304 floats (16 MB)
    float* Lbuf = Pbuf + 4194304;        // 131,072 floats
    short* aoF = xF;                     // reuse xF (consumed by qkv_mfma)

    x_relayout<<<2048, 256, 0, stream>>>(x, xF);
    w_relayout<<<256, 256, 0, stream>>>(W_qkv, W_out, wqF, woF);
    mask_relayout<<<dim3(16, 32), 256, 0, stream>>>(mask, maskF);
    qkv_mfma<<<1536, 256, 0, stream>>>(xF, wqF, b_qkv, qb, kbF, vbF);
    attn_mfma<<<2048, 256, 0, stream>>>(qb, kbF, vbF, maskF, Pbuf, Lbuf);
    attn_combine<<<1024, 256, 0, stream>>>(Pbuf, Lbuf, aoF);
    out_mfma<<<512, 256, 0, stream>>>(aoF, woF, b_out, out);
}

// Round 9
// 83.203 us; speedup vs baseline: 4.7297x; 1.2240x over previous
//
#include <hip/hip_runtime.h>
#include <hip/hip_bf16.h>

#define B_ 4
#define N_ 2048
#define C_ 256
#define H_ 8
#define D_ 32

typedef __attribute__((ext_vector_type(4))) short bf16x4;
typedef __attribute__((ext_vector_type(8))) short bf16x8;
typedef __attribute__((ext_vector_type(16))) float f32x16;

static __device__ __forceinline__ float b2f(short u) {
    unsigned v = ((unsigned)(unsigned short)u) << 16;
    return __builtin_bit_cast(float, v);
}
static __device__ __forceinline__ short f2bs(float f) {
    __hip_bfloat16 h = __float2bfloat16(f);
    return __builtin_bit_cast(short, h);
}

// Fragment k-map (32x32x16 bf16): slot s (0..15), lane-half hi:
//   dd = hi*4 + (s&3) + 8*(s>>2); inverse hi=(dd>>2)&1, s=(dd&3)+4*(dd>>3)
// REGISTER BUDGET NOTE: attn body = 128 live regs/thread = exactly the
// 4-waves/EU unified-RF budget. (256,8)/(256,6) caps and the R7 software
// pipeline all spilled to scratch (400-900MB). R8 split-m x2 across blocks
// didn't raise residency (VGPR-capped) and regressed 45->65us.
// Scale only via zero-register levers: XCD swizzle, setprio.

// ---------------------------------------------------------------------------
// Merged prep: x relayout (blocks 0..2047), W relayout (2048..2303),
// mask relayout (2304..2815). One launch instead of three.
// ---------------------------------------------------------------------------
__global__ __launch_bounds__(256) void prep_relayout(const float* __restrict__ x,
                                                     const float* __restrict__ Wq,
                                                     const float* __restrict__ Wo,
                                                     const float* __restrict__ mask,
                                                     short* __restrict__ xF,
                                                     short* __restrict__ wqF,
                                                     short* __restrict__ woF,
                                                     short* __restrict__ maskF) {
    const int t = threadIdx.x;
    const int b = blockIdx.x;
    if (b < 2048) {
        const int idx = b * 256 + t;
        const int row = idx >> 6, c0 = (idx & 63) * 4;
        const float4 f4 = *(const float4*)(x + (size_t)row * 256 + c0);
        const int mt = row >> 5, l5 = row & 31;
        const int kt = c0 >> 5, dd0 = c0 & 31;
        const int hi = (dd0 >> 2) & 1, s0 = 4 * (dd0 >> 3);
        bf16x4 o;
        o[0] = f2bs(f4.x); o[1] = f2bs(f4.y); o[2] = f2bs(f4.z); o[3] = f2bs(f4.w);
        *(bf16x4*)(xF + (((size_t)mt * 8 + kt) * 32 + l5) * 32 + hi * 16 + s0) = o;
    } else if (b < 2304) {
        int idx = (b - 2048) * 256 + t;
        const float* W; short* dst; int ncols;
        if (idx < 49152) { W = Wq; dst = wqF; ncols = 768; }
        else { idx -= 49152; W = Wo; dst = woF; ncols = 256; }
        const int f4pr = ncols >> 2;
        const int row = idx / f4pr, c0 = (idx % f4pr) * 4;
        const float4 f4 = *(const float4*)(W + (size_t)row * ncols + c0);
        const int kt = row >> 5, dd = row & 31;
        const int hi = (dd >> 2) & 1, s = (dd & 3) + 4 * (dd >> 3);
        const float vals[4] = {f4.x, f4.y, f4.z, f4.w};
#pragma unroll
        for (int j = 0; j < 4; ++j) {
            const int col = c0 + j, nt = col >> 5, l5 = col & 31;
            dst[(((size_t)nt * 8 + kt) * 32 + l5) * 32 + hi * 16 + s] = f2bs(vals[j]);
        }
    } else {
        const int bid = b - 2304;           // 0..511
        const int bx = bid & 15, by = bid >> 4;
        const int n = by * 64 + (t & 63);
        const int mt = bx * 4 + (t >> 6);
        const float cf = 0.17677669529663687f * 1.4426950408889634f;
        float v[32];
        const float4* src = (const float4*)(mask + (size_t)n * N_ + mt * 32);
#pragma unroll
        for (int i = 0; i < 8; ++i) {
            const float4 f4 = src[i];
            v[i * 4 + 0] = f4.x; v[i * 4 + 1] = f4.y;
            v[i * 4 + 2] = f4.z; v[i * 4 + 3] = f4.w;
        }
#pragma unroll
        for (int hi = 0; hi < 2; ++hi) {
            bf16x8 o0, o1;
#pragma unroll
            for (int r = 0; r < 16; ++r) {
                const int crow = (r & 3) + 8 * (r >> 2) + 4 * hi;
                const short s = f2bs(cf * (0.1f + 0.9f * v[crow]));
                if (r < 8) o0[r] = s; else o1[r - 8] = s;
            }
            short* dst = maskF + ((size_t)(mt * 2 + hi) * N_ + n) * 16;
            *(bf16x8*)dst = o0;
            *(bf16x8*)(dst + 8) = o1;
        }
    }
}

// ---------------------------------------------------------------------------
// QKV projection, MFMA (dual accumulator for MFMA ILP).
// ---------------------------------------------------------------------------
__global__ __launch_bounds__(256, 4) void qkv_mfma(const short* __restrict__ xF,
                                                   const short* __restrict__ wqF,
                                                   const float* __restrict__ bias,
                                                   short* __restrict__ qb,
                                                   short* __restrict__ kbF,
                                                   short* __restrict__ vbF) {
    __shared__ short sc[4][32 * 34];
    const int t = threadIdx.x;
    const int w = t >> 6, lane = t & 63, l5 = lane & 31, hi = lane >> 5;
    const int tile = blockIdx.x * 4 + w;
    const int nt = tile % 24, mt = tile / 24;
    f32x16 acc0, acc1;
#pragma unroll
    for (int i = 0; i < 16; ++i) { acc0[i] = 0.f; acc1[i] = 0.f; }
    const short* ap = xF + ((size_t)mt * 8 * 32) * 32 + l5 * 32 + hi * 16;
    const short* bp = wqF + ((size_t)nt * 8 * 32) * 32 + l5 * 32 + hi * 16;
#pragma unroll
    for (int kt = 0; kt < 8; kt += 2) {
        const bf16x8 a0 = *(const bf16x8*)(ap + kt * 1024);
        const bf16x8 a1 = *(const bf16x8*)(ap + kt * 1024 + 8);
        const bf16x8 b0 = *(const bf16x8*)(bp + kt * 1024);
        const bf16x8 b1 = *(const bf16x8*)(bp + kt * 1024 + 8);
        const bf16x8 a2 = *(const bf16x8*)(ap + kt * 1024 + 1024);
        const bf16x8 a3 = *(const bf16x8*)(ap + kt * 1024 + 1032);
        const bf16x8 b2 = *(const bf16x8*)(bp + kt * 1024 + 1024);
        const bf16x8 b3 = *(const bf16x8*)(bp + kt * 1024 + 1032);
        acc0 = __builtin_amdgcn_mfma_f32_32x32x16_bf16(a0, b0, acc0, 0, 0, 0);
        acc1 = __builtin_amdgcn_mfma_f32_32x32x16_bf16(a2, b2, acc1, 0, 0, 0);
        acc0 = __builtin_amdgcn_mfma_f32_32x32x16_bf16(a1, b1, acc0, 0, 0, 0);
        acc1 = __builtin_amdgcn_mfma_f32_32x32x16_bf16(a3, b3, acc1, 0, 0, 0);
    }
    const float bq = bias[nt * 32 + l5];
    short* myc = sc[w];
#pragma unroll
    for (int r = 0; r < 16; ++r)
        myc[((r & 3) + 8 * (r >> 2) + 4 * hi) * 34 + l5] =
            f2bs(acc0[r] + acc1[r] + bq);
    __syncthreads();

    const int h = nt & 7, t3 = nt >> 3;
    const int mtk = mt & 63;
    const size_t bh = (size_t)(mt >> 6) * 8 + h;
    if (t3 == 0) {
        const bf16x8 r0 = *(const bf16x8*)(myc + l5 * 34 + hi * 16);
        const bf16x8 r1 = *(const bf16x8*)(myc + l5 * 34 + hi * 16 + 8);
        short* dst = qb + (bh * N_ + (size_t)mtk * 32 + l5) * D_ + hi * 16;
        *(bf16x8*)dst = r0;
        *(bf16x8*)(dst + 8) = r1;
    } else if (t3 == 1) {
        bf16x8 o0, o1;
#pragma unroll
        for (int s = 0; s < 16; ++s) {
            const int dd = hi * 4 + (s & 3) + 8 * (s >> 2);
            const short vv = myc[l5 * 34 + dd];
            if (s < 8) o0[s] = vv; else o1[s - 8] = vv;
        }
        short* dst = kbF + ((bh * 64 + mtk) * 32 + l5) * 32 + hi * 16;
        *(bf16x8*)dst = o0;
        *(bf16x8*)(dst + 8) = o1;
    } else {
        bf16x8 o0, o1;
#pragma unroll
        for (int s = 0; s < 16; ++s) {
            const int nl = hi * 4 + (s & 3) + 8 * (s >> 2);
            const short vv = myc[nl * 34 + l5];
            if (s < 8) o0[s] = vv; else o1[s - 8] = vv;
        }
        short* dst = vbF + ((bh * 64 + mtk) * 32 + l5) * 32 + hi * 16;
        *(bf16x8*)dst = o0;
        *(bf16x8*)(dst + 8) = o1;
    }
}

// ---------------------------------------------------------------------------
// MFMA flash attention (R4 body, 44.9us proven). Grid 1024. Block = 4 waves
// (split-m x4 in-block), 64 q-rows (2-tile ILP). Direct aoF fragment write.
// + XCD swizzle: blocks of one bh colocate on one XCD (4 bh x 512KB KV = 2MB
//   working set fits the 4MB per-XCD L2; unswizzled each XCD streams 16MB).
// + s_setprio(1) around MFMA clusters (T5; waves are barrier-free in loop).
// ---------------------------------------------------------------------------
__global__ __launch_bounds__(256, 4) void attn_mfma(const short* __restrict__ qb,
                                                    const short* __restrict__ kbF,
                                                    const short* __restrict__ vbF,
                                                    const short* __restrict__ maskF,
                                                    short* __restrict__ aoF) {
    __shared__ float red[4][32][33];
    __shared__ float Ls[4][32];
    const int t = threadIdx.x;
    const int w = t >> 6, lane = t & 63, l5 = lane & 31, hi = lane >> 5;
    const int hi4 = hi * 4;
    const int vb = (blockIdx.x & 7) * 128 + (blockIdx.x >> 3);  // XCD swizzle
    const int bh = vb >> 5, qg = vb & 31;
    const int q0 = qg * 64;
    const int nqA = q0 + l5, nqB = q0 + 32 + l5;

    const short* qrA = qb + ((size_t)bh * N_ + nqA) * D_;
    const short* qrB = qb + ((size_t)bh * N_ + nqB) * D_;
    const bf16x8 qfA0 = __builtin_shufflevector(*(const bf16x4*)(qrA + hi4),
                                                *(const bf16x4*)(qrA + hi4 + 8),
                                                0, 1, 2, 3, 4, 5, 6, 7);
    const bf16x8 qfA1 = __builtin_shufflevector(*(const bf16x4*)(qrA + hi4 + 16),
                                                *(const bf16x4*)(qrA + hi4 + 24),
                                                0, 1, 2, 3, 4, 5, 6, 7);
    const bf16x8 qfB0 = __builtin_shufflevector(*(const bf16x4*)(qrB + hi4),
                                                *(const bf16x4*)(qrB + hi4 + 8),
                                                0, 1, 2, 3, 4, 5, 6, 7);
    const bf16x8 qfB1 = __builtin_shufflevector(*(const bf16x4*)(qrB + hi4 + 16),
                                                *(const bf16x4*)(qrB + hi4 + 24),
                                                0, 1, 2, 3, 4, 5, 6, 7);
    f32x16 accA, accB;
#pragma unroll
    for (int i = 0; i < 16; ++i) { accA[i] = 0.f; accB[i] = 0.f; }
    float lsA0 = 0.f, lsA1 = 0.f, lsB0 = 0.f, lsB1 = 0.f;

    const size_t fragbase = (size_t)bh * 64 * 1024;
#pragma unroll 4
    for (int i = 0; i < 16; ++i) {
        const int mt = w * 16 + i;
        // mask loads first (independent of MFMA results -> hoistable)
        const short* mpA = maskF + ((size_t)(mt * 2 + hi) * N_ + nqA) * 16;
        const short* mpB = maskF + ((size_t)(mt * 2 + hi) * N_ + nqB) * 16;
        const bf16x8 mA0 = *(const bf16x8*)mpA;
        const bf16x8 mA1 = *(const bf16x8*)(mpA + 8);
        const bf16x8 mB0 = *(const bf16x8*)mpB;
        const bf16x8 mB1 = *(const bf16x8*)(mpB + 8);
        const short* vp = vbF + fragbase + (size_t)mt * 1024 + l5 * 32 + hi * 16;
        const bf16x8 vf0 = *(const bf16x8*)vp;
        const bf16x8 vf1 = *(const bf16x8*)(vp + 8);

        const short* kp = kbF + fragbase + (size_t)mt * 1024 + l5 * 32 + hi * 16;
        const bf16x8 af0 = *(const bf16x8*)kp;
        const bf16x8 af1 = *(const bf16x8*)(kp + 8);
        f32x16 sA, sB;
#pragma unroll
        for (int j = 0; j < 16; ++j) { sA[j] = 0.f; sB[j] = 0.f; }
        __builtin_amdgcn_s_setprio(1);
        sA = __builtin_amdgcn_mfma_f32_32x32x16_bf16(af0, qfA0, sA, 0, 0, 0);
        sB = __builtin_amdgcn_mfma_f32_32x32x16_bf16(af0, qfB0, sB, 0, 0, 0);
        sA = __builtin_amdgcn_mfma_f32_32x32x16_bf16(af1, qfA1, sA, 0, 0, 0);
        sB = __builtin_amdgcn_mfma_f32_32x32x16_bf16(af1, qfB1, sB, 0, 0, 0);
        __builtin_amdgcn_s_setprio(0);

        bf16x8 pfA0, pfA1, pfB0, pfB1;
#pragma unroll
        for (int r = 0; r < 16; ++r) {
            const float fmA = b2f(r < 8 ? mA0[r] : mA1[r - 8]);
            const float fmB = b2f(r < 8 ? mB0[r] : mB1[r - 8]);
            const float pA = __builtin_amdgcn_exp2f(sA[r] * fmA);
            const float pB = __builtin_amdgcn_exp2f(sB[r] * fmB);
            if (r < 8) { lsA0 += pA; lsB0 += pB; }
            else       { lsA1 += pA; lsB1 += pB; }
            const short hA = f2bs(pA), hB = f2bs(pB);
            if (r < 8) { pfA0[r] = hA; pfB0[r] = hB; }
            else       { pfA1[r - 8] = hA; pfB1[r - 8] = hB; }
        }
        __builtin_amdgcn_s_setprio(1);
        accA = __builtin_amdgcn_mfma_f32_32x32x16_bf16(vf0, pfA0, accA, 0, 0, 0);
        accB = __builtin_amdgcn_mfma_f32_32x32x16_bf16(vf0, pfB0, accB, 0, 0, 0);
        accA = __builtin_amdgcn_mfma_f32_32x32x16_bf16(vf1, pfA1, accA, 0, 0, 0);
        accB = __builtin_amdgcn_mfma_f32_32x32x16_bf16(vf1, pfB1, accB, 0, 0, 0);
        __builtin_amdgcn_s_setprio(0);
    }
    const float lsA = lsA0 + lsA1, lsB = lsB0 + lsB1;

    // two reduction rounds (one per q-tile), reusing the same LDS buffer
    const int h = bh & 7;
    const int gmtb = (bh >> 3) * 64 + qg * 2;
#pragma unroll
    for (int tq = 0; tq < 2; ++tq) {
        if (tq) __syncthreads();
        const float lsum = tq ? lsB : lsA;
        const f32x16 acc = tq ? accB : accA;
        const float lt = lsum + __shfl_xor(lsum, 32);
        Ls[w][l5] = lt;
#pragma unroll
        for (int r = 0; r < 16; ++r)
            red[w][(r & 3) + 8 * (r >> 2) + hi4][l5] = acc[r];
        __syncthreads();
        const int row = t & 31, hi2 = (t >> 5) & 1, sh = t >> 6;
        const float inv = 1.0f / (Ls[0][row] + Ls[1][row] + Ls[2][row] + Ls[3][row]);
        bf16x4 o;
#pragma unroll
        for (int j = 0; j < 4; ++j) {
            const int dd = hi2 * 4 + j + 8 * sh;
            o[j] = f2bs((red[0][dd][row] + red[1][dd][row] +
                         red[2][dd][row] + red[3][dd][row]) * inv);
        }
        const size_t gmt = gmtb + tq;
        *(bf16x4*)(aoF + ((gmt * 8 + h) * 32 + row) * 32 + hi2 * 16 + sh * 4) = o;
    }
}

// ---------------------------------------------------------------------------
// Output projection, MFMA (dual accumulator).
// ---------------------------------------------------------------------------
__global__ __launch_bounds__(256, 4) void out_mfma(const short* __restrict__ aoF,
                                                   const short* __restrict__ woF,
                                                   const float* __restrict__ bias,
                                                   float* __restrict__ out) {
    const int t = threadIdx.x;
    const int w = t >> 6, lane = t & 63, l5 = lane & 31, hi = lane >> 5;
    const int tile = blockIdx.x * 4 + w;
    const int nt = tile & 7, mt = tile >> 3;
    f32x16 acc0, acc1;
#pragma unroll
    for (int i = 0; i < 16; ++i) { acc0[i] = 0.f; acc1[i] = 0.f; }
    const short* ap = aoF + (size_t)mt * 8192 + l5 * 32 + hi * 16;
    const short* bp = woF + (size_t)nt * 8192 + l5 * 32 + hi * 16;
#pragma unroll
    for (int kt = 0; kt < 8; kt += 2) {
        const bf16x8 a0 = *(const bf16x8*)(ap + kt * 1024);
        const bf16x8 a1 = *(const bf16x8*)(ap + kt * 1024 + 8);
        const bf16x8 b0 = *(const bf16x8*)(bp + kt * 1024);
        const bf16x8 b1 = *(const bf16x8*)(bp + kt * 1024 + 8);
        const bf16x8 a2 = *(const bf16x8*)(ap + kt * 1024 + 1024);
        const bf16x8 a3 = *(const bf16x8*)(ap + kt * 1024 + 1032);
        const bf16x8 b2 = *(const bf16x8*)(bp + kt * 1024 + 1024);
        const bf16x8 b3 = *(const bf16x8*)(bp + kt * 1024 + 1032);
        acc0 = __builtin_amdgcn_mfma_f32_32x32x16_bf16(a0, b0, acc0, 0, 0, 0);
        acc1 = __builtin_amdgcn_mfma_f32_32x32x16_bf16(a2, b2, acc1, 0, 0, 0);
        acc0 = __builtin_amdgcn_mfma_f32_32x32x16_bf16(a1, b1, acc0, 0, 0, 0);
        acc1 = __builtin_amdgcn_mfma_f32_32x32x16_bf16(a3, b3, acc1, 0, 0, 0);
    }
    const float bo = bias[nt * 32 + l5];
#pragma unroll
    for (int r = 0; r < 16; ++r) {
        const int crow = (r & 3) + 8 * (r >> 2) + 4 * hi;
        out[(size_t)(mt * 32 + crow) * 256 + nt * 32 + l5] =
            acc0[r] + acc1[r] + bo;
    }
}

extern "C" void kernel_launch(void* const* d_in, const int* in_sizes, int n_in,
                              void* d_out, int out_size, void* d_ws, size_t ws_size,
                              hipStream_t stream) {
    const float* x = (const float*)d_in[0];
    const float* mask = (const float*)d_in[1];
    const float* W_qkv = (const float*)d_in[2];
    const float* b_qkv = (const float*)d_in[3];
    const float* W_out = (const float*)d_in[4];
    const float* b_out = (const float*)d_in[5];
    float* out = (float*)d_out;

    const size_t per = (size_t)B_ * H_ * N_ * D_;  // 2,097,152
    short* qb = (short*)d_ws;
    short* kbF = qb + per;
    short* vbF = kbF + per;
    short* maskF = vbF + per;            // N*N = 4,194,304 shorts
    short* xF = maskF + (size_t)N_ * N_; // 2,097,152 shorts
    short* wqF = xF + per;               // 196,608 shorts
    short* woF = wqF + 196608;           // 65,536 shorts
    short* aoF = xF;                     // reuse xF (consumed by qkv_mfma)

    prep_relayout<<<2816, 256, 0, stream>>>(x, W_qkv, W_out, mask,
                                            xF, wqF, woF, maskF);
    qkv_mfma<<<1536, 256, 0, stream>>>(xF, wqF, b_qkv, qb, kbF, vbF);
    attn_mfma<<<1024, 256, 0, stream>>>(qb, kbF, vbF, maskF, aoF);
    out_mfma<<<512, 256, 0, stream>>>(aoF, woF, b_out, out);
}